// Round 8
// baseline (420.523 us; speedup 1.0000x reference)
//
#include <hip/hip_runtime.h>

// Guided filter, r=8, eps=0.01, (8,3,1024,1024) fp32.
//
// Two-pass split, ROWS=32, double-buffered stage (1 barrier/row).
// R2/R6/R7 post-mortem: runtime tracks HBM traffic at a pinned ~2.8 TB/s in
// every config (occupancy x2 null, barrier/2 null) -> duty-cycle-limited:
// __syncthreads() = s_waitcnt vmcnt(0)+s_barrier force-drains the prefetch
// loads issued ~10 instrs earlier, every row. THIS ROUND: raw LDS-only
// barrier (s_waitcnt lgkmcnt(0); s_barrier) keeps global loads/stores in
// flight across the barrier (guide T3/T4, m201 pattern). Safe: no
// cross-thread global deps in-kernel; same-thread load uses get compiler
// counted vmcnt; LDS WAR protected by per-wave lgkmcnt(0) at each barrier
// + parity double-buffer.
// Fallback fused kernel (verified 338 us) unchanged.

namespace {
constexpr int RAD  = 8;
constexpr int H    = 1024;
constexpr int W    = 1024;
constexpr int NSL  = 24;             // 8*3 slices
constexpr int ROWS = 32;             // output rows per block
constexpr int PW   = W + 2 * RAD;    // padded LDS row width (1040)
constexpr float EPS_C = 0.01f;
constexpr int GRID = NSL * (H / ROWS);  // 768 blocks = 3/CU
constexpr size_t IMG = (size_t)NSL * H * W;  // floats per image stack
}

__device__ __forceinline__ float frcp(float v) { return __builtin_amdgcn_rcpf(v); }
__device__ __forceinline__ float4 z4() { return make_float4(0.f, 0.f, 0.f, 0.f); }

// LDS-only barrier: orders LDS ops across the workgroup WITHOUT draining
// outstanding global loads/stores (vmcnt stays counted -> prefetch latency
// hides under compute). Memory clobbers fence compiler reordering.
__device__ __forceinline__ void lds_barrier() {
  asm volatile("s_waitcnt lgkmcnt(0)" ::: "memory");
  __builtin_amdgcn_s_barrier();
  asm volatile("" ::: "memory");
}

struct V4 { float4 x, y, xy, xx; };

__device__ __forceinline__ void vzero(V4& S) { S.x = z4(); S.y = z4(); S.xy = z4(); S.xx = z4(); }

__device__ __forceinline__ void vadd(V4& S, const float4 xv, const float4 yv) {
  S.x.x += xv.x; S.x.y += xv.y; S.x.z += xv.z; S.x.w += xv.w;
  S.y.x += yv.x; S.y.y += yv.y; S.y.z += yv.z; S.y.w += yv.w;
  S.xy.x += xv.x * yv.x; S.xy.y += xv.y * yv.y; S.xy.z += xv.z * yv.z; S.xy.w += xv.w * yv.w;
  S.xx.x += xv.x * xv.x; S.xx.y += xv.y * xv.y; S.xx.z += xv.z * xv.z; S.xx.w += xv.w * xv.w;
}

__device__ __forceinline__ void vsub(V4& S, const float4 xv, const float4 yv) {
  S.x.x -= xv.x; S.x.y -= xv.y; S.x.z -= xv.z; S.x.w -= xv.w;
  S.y.x -= yv.x; S.y.y -= yv.y; S.y.z -= yv.z; S.y.w -= yv.w;
  S.xy.x -= xv.x * yv.x; S.xy.y -= xv.y * yv.y; S.xy.z -= xv.z * yv.z; S.xy.w -= xv.w * yv.w;
  S.xx.x -= xv.x * xv.x; S.xx.y -= xv.y * xv.y; S.xx.z -= xv.z * xv.z; S.xx.w -= xv.w * xv.w;
}

// XCD-contiguous 128-row regions (32-row bands)
__device__ __forceinline__ void map_block(int g, int& slice, int& r0) {
  const int xcd = g & 7;
  const int i = g >> 3;                // [0,96)
  const int band = xcd * 4 + (i & 3);  // [0,32)
  slice = i >> 2;                      // [0,24)
  r0 = band * ROWS;
}

// 17-tap horizontal box sums for 4 consecutive cols from a zero-padded LDS
// row (16B lane stride -> conflict-free b128 reads).
__device__ __forceinline__ void hbox(const float* buf, int c0, float o[4]) {
  const float4 va = *reinterpret_cast<const float4*>(buf + c0);
  const float4 vb = *reinterpret_cast<const float4*>(buf + c0 + 4);
  const float4 vc = *reinterpret_cast<const float4*>(buf + c0 + 8);
  const float4 vd = *reinterpret_cast<const float4*>(buf + c0 + 12);
  const float4 ve = *reinterpret_cast<const float4*>(buf + c0 + 16);
  const float w[20] = {va.x, va.y, va.z, va.w, vb.x, vb.y, vb.z, vb.w,
                       vc.x, vc.y, vc.z, vc.w, vd.x, vd.y, vd.z, vd.w,
                       ve.x, ve.y, ve.z, ve.w};
  float s = w[0];
#pragma unroll
  for (int k = 1; k <= 16; ++k) s += w[k];
  o[0] = s;
  o[1] = o[0] - w[0] + w[17];
  o[2] = o[1] - w[1] + w[18];
  o[3] = o[2] - w[2] + w[19];
}

__device__ __forceinline__ float inv_cnt(int p) {
  int lo = p - RAD < 0 ? 0 : p - RAD;
  int hi = p + RAD > H - 1 ? H - 1 : p + RAD;
  return frcp((float)(hi - lo + 1));
}

__device__ __forceinline__ float4 ldrow(const float* __restrict__ s, int r, int c0) {
  return *reinterpret_cast<const float4*>(s + (size_t)r * W + c0);
}

__device__ __forceinline__ void publish(float* fbase, int c0, const V4& S) {
  *reinterpret_cast<float4*>(&fbase[0 * PW + RAD + c0]) = S.x;
  *reinterpret_cast<float4*>(&fbase[1 * PW + RAD + c0]) = S.y;
  *reinterpret_cast<float4*>(&fbase[2 * PW + RAD + c0]) = S.xy;
  *reinterpret_cast<float4*>(&fbase[3 * PW + RAD + c0]) = S.xx;
}

__device__ __forceinline__ void compute_ab(const float* fbase, int c0, float invcy,
                                           const float invcx[4], float av[4], float bv[4]) {
  float bx[4], by[4], bxy[4], bxx[4];
  hbox(fbase + 0 * PW, c0, bx);
  hbox(fbase + 1 * PW, c0, by);
  hbox(fbase + 2 * PW, c0, bxy);
  hbox(fbase + 3 * PW, c0, bxx);
#pragma unroll
  for (int j = 0; j < 4; ++j) {
    const float invN = invcy * invcx[j];
    const float mx = bx[j] * invN;
    const float my = by[j] * invN;
    const float cov = bxy[j] * invN - mx * my;
    const float var = bxx[j] * invN - mx * mx;
    const float a = cov * frcp(var + EPS_C);
    av[j] = a;
    bv[j] = my - a * mx;
  }
}

__device__ __forceinline__ void publish2(float* sbase, int c0, const float av[4], const float bv[4]) {
  *reinterpret_cast<float4*>(&sbase[RAD + c0]) = make_float4(av[0], av[1], av[2], av[3]);
  *reinterpret_cast<float4*>(&sbase[PW + RAD + c0]) = make_float4(bv[0], bv[1], bv[2], bv[3]);
}

__device__ __forceinline__ void hbox2(const float* sbase, int c0, float HA[4], float HB[4]) {
  hbox(sbase, c0, HA);
  hbox(sbase + PW, c0, HB);
}

__device__ __forceinline__ void setup_invcx(int c0, float invcx[4]) {
#pragma unroll
  for (int j = 0; j < 4; ++j) {
    const int c = c0 + j;
    const int cl = c - RAD < 0 ? 0 : c - RAD;
    const int ch = c + RAD > W - 1 ? W - 1 : c + RAD;
    invcx[j] = frcp((float)(ch - cl + 1));
  }
}

// ---------------------------------------------------------------------------
// Pass 1: a,b images. Dbuf stage, 1 LDS-only barrier/row. 32-row bands.
// ---------------------------------------------------------------------------
__global__ __launch_bounds__(256, 3) void k_ab(
    const float* __restrict__ x, const float* __restrict__ y,
    float* __restrict__ ag, float* __restrict__ bg) {
  __shared__ float stage[2][4 * PW];  // dbuf of vertical sums {x,y,xy,xx}

  const int t = threadIdx.x;
  int slice, r0;
  map_block(blockIdx.x, slice, r0);
  const size_t soff = (size_t)slice * H * W;
  const float* xs = x + soff;
  const float* ys = y + soff;
  float* as = ag + soff;
  float* bs = bg + soff;
  const int c0 = t << 2;

  // zero halo pads of both buffers' 4 stage rows (persist for whole kernel)
  if (t < 128) {
    const int b = t >> 6;            // buffer
    const int j = (t >> 4) & 3;      // stat row
    const int q = t & 15;
    const int pos = (q < 8) ? q : (W + RAD + (q - 8));
    stage[b][j * PW + pos] = 0.f;
  }

  float invcx[4];
  setup_invcx(c0, invcx);

  // build vertical sums centered at p = r0 (rows clamped at top edge)
  V4 SL; vzero(SL);
  {
    int lo = r0 - RAD < 0 ? 0 : r0 - RAD;
    for (int rr = lo; rr <= r0 + RAD; ++rr)
      vadd(SL, ldrow(xs, rr, c0), ldrow(ys, rr, c0));
  }

  int par = 0;
  for (int p = r0; p < r0 + ROWS; ++p) {
    // prefetch slide rows; stay in flight across the LDS barrier, consumed
    // at the bottom (compiler inserts the counted vmcnt before use)
    float4 xa = z4(), ya = z4(), xr = z4(), yr = z4();
    if (p + 9 <= H - 1) { xa = ldrow(xs, p + 9, c0); ya = ldrow(ys, p + 9, c0); }
    if (p - RAD >= 0)   { xr = ldrow(xs, p - RAD, c0); yr = ldrow(ys, p - RAD, c0); }

    publish(stage[par], c0, SL);
    lds_barrier();  // LDS-only: no vmcnt drain

    float av[4], bv[4];
    compute_ab(stage[par], c0, inv_cnt(p), invcx, av, bv);
    *reinterpret_cast<float4*>(as + (size_t)p * W + c0) = make_float4(av[0], av[1], av[2], av[3]);
    *reinterpret_cast<float4*>(bs + (size_t)p * W + c0) = make_float4(bv[0], bv[1], bv[2], bv[3]);

    vadd(SL, xa, ya);
    vsub(SL, xr, yr);
    par ^= 1;  // next publish goes to the other buffer (parity protects WAR)
  }
}

// ---------------------------------------------------------------------------
// Pass 2: out = box(a)/N * x + box(b)/N. Register vertical sums of a,b,
// dbuf srow, 1 LDS-only barrier/row. 32-row bands.
// ---------------------------------------------------------------------------
__global__ __launch_bounds__(256, 3) void k_out(
    const float* __restrict__ ag, const float* __restrict__ bg,
    const float* __restrict__ x, float* __restrict__ out) {
  __shared__ float srow[2][2 * PW];  // dbuf of vertical sums of a,b

  const int t = threadIdx.x;
  int slice, r0;
  map_block(blockIdx.x, slice, r0);
  const size_t soff = (size_t)slice * H * W;
  const float* as = ag + soff;
  const float* bs = bg + soff;
  const float* xs = x + soff;
  float* os = out + soff;
  const int c0 = t << 2;

  if (t < 64) {
    const int b = t >> 5;            // buffer
    const int j = (t >> 4) & 1;      // row (a or b)
    const int q = t & 15;
    const int pos = (q < 8) ? q : (W + RAD + (q - 8));
    srow[b][j * PW + pos] = 0.f;
  }

  float invcx[4];
  setup_invcx(c0, invcx);

  float4 Va = z4(), Vb = z4();
  {
    int lo = r0 - RAD < 0 ? 0 : r0 - RAD;
    for (int rr = lo; rr <= r0 + RAD; ++rr) {
      const float4 a4 = ldrow(as, rr, c0);
      const float4 b4 = ldrow(bs, rr, c0);
      Va.x += a4.x; Va.y += a4.y; Va.z += a4.z; Va.w += a4.w;
      Vb.x += b4.x; Vb.y += b4.y; Vb.z += b4.z; Vb.w += b4.w;
    }
  }

  int par = 0;
  for (int k = r0; k < r0 + ROWS; ++k) {
    const float4 xk = ldrow(xs, k, c0);
    float4 aa = z4(), ba = z4(), ar = z4(), br = z4();
    if (k + 9 <= H - 1) { aa = ldrow(as, k + 9, c0); ba = ldrow(bs, k + 9, c0); }
    if (k - RAD >= 0)   { ar = ldrow(as, k - RAD, c0); br = ldrow(bs, k - RAD, c0); }

    *reinterpret_cast<float4*>(&srow[par][0 * PW + RAD + c0]) = Va;
    *reinterpret_cast<float4*>(&srow[par][1 * PW + RAD + c0]) = Vb;
    lds_barrier();  // LDS-only: prefetched a/b/x loads stay in flight

    float HA[4], HB[4];
    hbox(srow[par], c0, HA);
    hbox(srow[par] + PW, c0, HB);

    const float invcy = inv_cnt(k);
    const float n0 = invcy * invcx[0], n1 = invcy * invcx[1];
    const float n2 = invcy * invcx[2], n3 = invcy * invcx[3];
    float4 o;
    o.x = HA[0] * n0 * xk.x + HB[0] * n0;
    o.y = HA[1] * n1 * xk.y + HB[1] * n1;
    o.z = HA[2] * n2 * xk.z + HB[2] * n2;
    o.w = HA[3] * n3 * xk.w + HB[3] * n3;
    *reinterpret_cast<float4*>(os + (size_t)k * W + c0) = o;

    Va.x += aa.x - ar.x; Va.y += aa.y - ar.y; Va.z += aa.z - ar.z; Va.w += aa.w - ar.w;
    Vb.x += ba.x - br.x; Vb.y += ba.y - br.y; Vb.z += ba.z - br.z; Vb.w += ba.w - br.w;
    par ^= 1;
  }
}

// ---------------------------------------------------------------------------
// Fallback: the previous verified fused kernel (dual-pipeline recompute),
// used when the workspace cannot hold the a,b intermediate (201 MB).
// ---------------------------------------------------------------------------
__global__ __launch_bounds__(256, 3) void k_fused(
    const float* __restrict__ x, const float* __restrict__ y, float* __restrict__ out) {
  __shared__ float stage[12 * PW];  // 49,920 B: fL[4] fG[4] sL[2] sG[2]
  float* fL = stage;
  float* fG = stage + 4 * PW;
  float* sL = stage + 8 * PW;
  float* sG = stage + 10 * PW;

  const int t = threadIdx.x;
  int slice, r0;
  map_block(blockIdx.x, slice, r0);
  const size_t soff = (size_t)slice * H * W;
  const float* xs = x + soff;
  const float* ys = y + soff;
  float* os = out + soff;
  const int c0 = t << 2;

  if (t < 96) {
    const int j = t >> 3, tt = t & 7;
    stage[j * PW + tt] = 0.f;
    stage[j * PW + W + RAD + tt] = 0.f;
  }

  float invcx[4];
  setup_invcx(c0, invcx);

  const int cstart = (r0 - 9 < 0) ? 0 : (r0 - 9);
  V4 SL; vzero(SL);
  {
    int lo = cstart - RAD; if (lo < 0) lo = 0;
    for (int rr = lo; rr <= cstart + RAD; ++rr) {
      vadd(SL, ldrow(xs, rr, c0), ldrow(ys, rr, c0));
    }
  }
  V4 SG;
  if (r0 == 0) vzero(SG); else SG = SL;
  float4 Sa = z4(), Sb = z4();

  __syncthreads();

  for (int c = cstart; c <= r0 + 7; ++c) {
    const float4 xa = ldrow(xs, c + 9, c0), ya = ldrow(ys, c + 9, c0);
    float4 xr = z4(), yr = z4();
    if (c - RAD >= 0) { xr = ldrow(xs, c - RAD, c0); yr = ldrow(ys, c - RAD, c0); }

    publish(fL, c0, SL);
    __syncthreads();
    float av[4], bv[4];
    compute_ab(fL, c0, inv_cnt(c), invcx, av, bv);
    publish2(sL, c0, av, bv);
    __syncthreads();
    float HA[4], HB[4];
    hbox2(sL, c0, HA, HB);
    Sa.x += HA[0]; Sa.y += HA[1]; Sa.z += HA[2]; Sa.w += HA[3];
    Sb.x += HB[0]; Sb.y += HB[1]; Sb.z += HB[2]; Sb.w += HB[3];
    vadd(SL, xa, ya);
    vsub(SL, xr, yr);
    __syncthreads();
  }

  for (int k = r0; k < r0 + ROWS; ++k) {
    const float4 xk = ldrow(xs, k, c0), yk = ldrow(ys, k, c0);
    float4 xt = z4(), yt = z4(), xb = z4(), yb = z4();
    if (k + 17 < H)  { xt = ldrow(xs, k + 17, c0); yt = ldrow(ys, k + 17, c0); }
    if (k - 17 >= 0) { xb = ldrow(xs, k - 17, c0); yb = ldrow(ys, k - 17, c0); }

    publish(fL, c0, SL);
    publish(fG, c0, SG);
    __syncthreads();  // A

    const int p = k + 8, q = k - 9;
    float avL[4], bvL[4], avG[4], bvG[4];
    compute_ab(fL, c0, inv_cnt(p), invcx, avL, bvL);
    compute_ab(fG, c0, inv_cnt(q), invcx, avG, bvG);
    publish2(sL, c0, avL, bvL);
    publish2(sG, c0, avG, bvG);
    __syncthreads();  // B

    float HAL[4], HBL[4], HAG[4], HBG[4];
    hbox2(sL, c0, HAL, HBL);
    hbox2(sG, c0, HAG, HBG);
    if (p <= H - 1) {
      Sa.x += HAL[0]; Sa.y += HAL[1]; Sa.z += HAL[2]; Sa.w += HAL[3];
      Sb.x += HBL[0]; Sb.y += HBL[1]; Sb.z += HBL[2]; Sb.w += HBL[3];
    }
    if (q >= 0) {
      Sa.x -= HAG[0]; Sa.y -= HAG[1]; Sa.z -= HAG[2]; Sa.w -= HAG[3];
      Sb.x -= HBG[0]; Sb.y -= HBG[1]; Sb.z -= HBG[2]; Sb.w -= HBG[3];
    }

    const float invcy = inv_cnt(k);
    const float n0 = invcy * invcx[0], n1 = invcy * invcx[1];
    const float n2 = invcy * invcx[2], n3 = invcy * invcx[3];
    float4 o;
    o.x = Sa.x * n0 * xk.x + Sb.x * n0;
    o.y = Sa.y * n1 * xk.y + Sb.y * n1;
    o.z = Sa.z * n2 * xk.z + Sb.z * n2;
    o.w = Sa.w * n3 * xk.w + Sb.w * n3;
    *reinterpret_cast<float4*>(os + (size_t)k * W + c0) = o;

    vadd(SL, xt, yt);
    vsub(SL, xk, yk);
    vadd(SG, xk, yk);
    vsub(SG, xb, yb);
    __syncthreads();  // C
  }
}

extern "C" void kernel_launch(void* const* d_in, const int* in_sizes, int n_in,
                              void* d_out, int out_size, void* d_ws, size_t ws_size,
                              hipStream_t stream) {
  const float* x = (const float*)d_in[0];
  const float* y = (const float*)d_in[1];
  float* out = (float*)d_out;
  const size_t need = 2 * IMG * sizeof(float);  // a,b intermediates (201 MB)
  if (d_ws != nullptr && ws_size >= need) {
    float* ag = (float*)d_ws;
    float* bg = ag + IMG;
    k_ab<<<GRID, 256, 0, stream>>>(x, y, ag, bg);
    k_out<<<GRID, 256, 0, stream>>>(ag, bg, x, out);
  } else {
    k_fused<<<GRID, 256, 0, stream>>>(x, y, out);
  }
}

// Round 12
// 406.861 us; speedup vs baseline: 1.0336x; 1.0336x over previous
//
#include <hip/hip_runtime.h>

// Guided filter, r=8, eps=0.01, (8,3,1024,1024) fp32.
//
// BARRIER-FREE two-pass split. R6/R7/R8 ledger: occupancy x2 null, barrier/2
// regressed, LDS-only barrier regressed -- BW pinned at 2.6-2.9 TB/s in every
// barrier'd config. Shared invariant: CU-wide s_barrier phase-locks all waves
// each row. THIS ROUND: wave-private staging. The 17-tap horizontal window
// spans only +-2 lanes, so each wave keeps vertical running sums for its
// 256-col strip PLUS a redundantly-maintained 16-col halo (lanes 0-3 carry an
// extra V4; halo loads duplicate neighbor-wave loads, +6% reads). Wave writes
// its private 272-col LDS rows, reads them back -- intra-wave DS ordering by
// lgkmcnt only, ZERO s_barrier. Waves free-run; compiler can pipeline across
// iterations. Halo slots rewritten each row (zero at edges = pad semantics).
// Fallback fused kernel (verified 338 us) unchanged.

namespace {
constexpr int RAD  = 8;
constexpr int H    = 1024;
constexpr int W    = 1024;
constexpr int NSL  = 24;             // 8*3 slices
constexpr int ROWS = 32;             // output rows per block
constexpr int PW   = W + 2 * RAD;    // fused-kernel LDS row width (1040)
constexpr int WSTR = 272;            // wave-private stage row width (256+16)
constexpr float EPS_C = 0.01f;
constexpr int GRID = NSL * (H / ROWS);  // 768 blocks = 3/CU
constexpr size_t IMG = (size_t)NSL * H * W;  // floats per image stack
}

__device__ __forceinline__ float frcp(float v) { return __builtin_amdgcn_rcpf(v); }
__device__ __forceinline__ float4 z4() { return make_float4(0.f, 0.f, 0.f, 0.f); }

struct V4 { float4 x, y, xy, xx; };

__device__ __forceinline__ void vzero(V4& S) { S.x = z4(); S.y = z4(); S.xy = z4(); S.xx = z4(); }

__device__ __forceinline__ void vadd(V4& S, const float4 xv, const float4 yv) {
  S.x.x += xv.x; S.x.y += xv.y; S.x.z += xv.z; S.x.w += xv.w;
  S.y.x += yv.x; S.y.y += yv.y; S.y.z += yv.z; S.y.w += yv.w;
  S.xy.x += xv.x * yv.x; S.xy.y += xv.y * yv.y; S.xy.z += xv.z * yv.z; S.xy.w += xv.w * yv.w;
  S.xx.x += xv.x * xv.x; S.xx.y += xv.y * xv.y; S.xx.z += xv.z * xv.z; S.xx.w += xv.w * xv.w;
}

__device__ __forceinline__ void vsub(V4& S, const float4 xv, const float4 yv) {
  S.x.x -= xv.x; S.x.y -= xv.y; S.x.z -= xv.z; S.x.w -= xv.w;
  S.y.x -= yv.x; S.y.y -= yv.y; S.y.z -= yv.z; S.y.w -= yv.w;
  S.xy.x -= xv.x * yv.x; S.xy.y -= xv.y * yv.y; S.xy.z -= xv.z * yv.z; S.xy.w -= xv.w * yv.w;
  S.xx.x -= xv.x * xv.x; S.xx.y -= xv.y * xv.y; S.xx.z -= xv.z * xv.z; S.xx.w -= xv.w * xv.w;
}

// XCD-contiguous 128-row regions (32-row bands)
__device__ __forceinline__ void map_block(int g, int& slice, int& r0) {
  const int xcd = g & 7;
  const int i = g >> 3;                // [0,96)
  const int band = xcd * 4 + (i & 3);  // [0,32)
  slice = i >> 2;                      // [0,24)
  r0 = band * ROWS;
}

// 17-tap horizontal box sums for 4 consecutive cols from a zero-padded LDS
// row (16B lane stride -> conflict-free b128 reads).
__device__ __forceinline__ void hbox(const float* buf, int c0, float o[4]) {
  const float4 va = *reinterpret_cast<const float4*>(buf + c0);
  const float4 vb = *reinterpret_cast<const float4*>(buf + c0 + 4);
  const float4 vc = *reinterpret_cast<const float4*>(buf + c0 + 8);
  const float4 vd = *reinterpret_cast<const float4*>(buf + c0 + 12);
  const float4 ve = *reinterpret_cast<const float4*>(buf + c0 + 16);
  const float w[20] = {va.x, va.y, va.z, va.w, vb.x, vb.y, vb.z, vb.w,
                       vc.x, vc.y, vc.z, vc.w, vd.x, vd.y, vd.z, vd.w,
                       ve.x, ve.y, ve.z, ve.w};
  float s = w[0];
#pragma unroll
  for (int k = 1; k <= 16; ++k) s += w[k];
  o[0] = s;
  o[1] = o[0] - w[0] + w[17];
  o[2] = o[1] - w[1] + w[18];
  o[3] = o[2] - w[2] + w[19];
}

__device__ __forceinline__ float inv_cnt(int p) {
  int lo = p - RAD < 0 ? 0 : p - RAD;
  int hi = p + RAD > H - 1 ? H - 1 : p + RAD;
  return frcp((float)(hi - lo + 1));
}

__device__ __forceinline__ float4 ldrow(const float* __restrict__ s, int r, int c0) {
  return *reinterpret_cast<const float4*>(s + (size_t)r * W + c0);
}

// ab math from a wave-private 4-stat stage (stride WSTR), local offset j0
__device__ __forceinline__ void compute_ab_w(const float* wb, int j0, float invcy,
                                             const float invcx[4], float av[4], float bv[4]) {
  float bx[4], by[4], bxy[4], bxx[4];
  hbox(wb + 0 * WSTR, j0, bx);
  hbox(wb + 1 * WSTR, j0, by);
  hbox(wb + 2 * WSTR, j0, bxy);
  hbox(wb + 3 * WSTR, j0, bxx);
#pragma unroll
  for (int j = 0; j < 4; ++j) {
    const float invN = invcy * invcx[j];
    const float mx = bx[j] * invN;
    const float my = by[j] * invN;
    const float cov = bxy[j] * invN - mx * my;
    const float var = bxx[j] * invN - mx * mx;
    const float a = cov * frcp(var + EPS_C);
    av[j] = a;
    bv[j] = my - a * mx;
  }
}

__device__ __forceinline__ void setup_invcx(int c0, float invcx[4]) {
#pragma unroll
  for (int j = 0; j < 4; ++j) {
    const int c = c0 + j;
    const int cl = c - RAD < 0 ? 0 : c - RAD;
    const int ch = c + RAD > W - 1 ? W - 1 : c + RAD;
    invcx[j] = frcp((float)(ch - cl + 1));
  }
}

// ---------------------------------------------------------------------------
// Pass 1: a,b images. Wave-private stage, NO barriers. 32-row bands.
// ---------------------------------------------------------------------------
__global__ __launch_bounds__(256, 3) void k_ab(
    const float* __restrict__ x, const float* __restrict__ y,
    float* __restrict__ ag, float* __restrict__ bg) {
  __shared__ float stg[4][4][WSTR];  // [wave][stat][272]  17.4 KB

  const int t = threadIdx.x;
  const int lane = t & 63;
  const int wid = t >> 6;
  const int wavebase = wid << 8;          // 256 cols per wave
  const int c0 = wavebase + (lane << 2);  // lane's 4 output cols
  const int j0 = lane << 2;               // local read offset (window start)

  int slice, r0;
  map_block(blockIdx.x, slice, r0);
  const size_t soff = (size_t)slice * H * W;
  const float* xs = x + soff;
  const float* ys = y + soff;
  float* as = ag + soff;
  float* bs = bg + soff;

  // halo role for lanes 0-3: 4 cols each, left 8 + right 8 of the strip
  const int hc = (lane < 2) ? (wavebase - 8 + (lane << 2))
                            : (wavebase + 256 + ((lane - 2) << 2));
  const bool hvalid = (lane < 4) && hc >= 0 && hc < W;
  const int hj = (lane < 2) ? (lane << 2) : (264 + ((lane - 2) << 2));

  float invcx[4];
  setup_invcx(c0, invcx);

  // warmup vertical sums centered p = r0 (rows clamped at top)
  V4 SL; vzero(SL);
  V4 HS; vzero(HS);
  {
    int lo = r0 - RAD < 0 ? 0 : r0 - RAD;
    for (int rr = lo; rr <= r0 + RAD; ++rr) {
      vadd(SL, ldrow(xs, rr, c0), ldrow(ys, rr, c0));
      if (hvalid) vadd(HS, ldrow(xs, rr, hc), ldrow(ys, rr, hc));
    }
  }

  float* wb = &stg[wid][0][0];
  for (int p = r0; p < r0 + ROWS; ++p) {
    // prefetch slide rows (consumed at the bottom; no barrier in between)
    float4 xa = z4(), ya = z4(), xr = z4(), yr = z4();
    float4 hxa = z4(), hya = z4(), hxr = z4(), hyr = z4();
    if (p + 9 <= H - 1) {
      xa = ldrow(xs, p + 9, c0); ya = ldrow(ys, p + 9, c0);
      if (hvalid) { hxa = ldrow(xs, p + 9, hc); hya = ldrow(ys, p + 9, hc); }
    }
    if (p - RAD >= 0) {
      xr = ldrow(xs, p - RAD, c0); yr = ldrow(ys, p - RAD, c0);
      if (hvalid) { hxr = ldrow(xs, p - RAD, hc); hyr = ldrow(ys, p - RAD, hc); }
    }

    // publish wave-private (primary at j=8+4*lane, halo at hj by lanes 0-3)
    const int jp = 8 + (lane << 2);
    *reinterpret_cast<float4*>(wb + 0 * WSTR + jp) = SL.x;
    *reinterpret_cast<float4*>(wb + 1 * WSTR + jp) = SL.y;
    *reinterpret_cast<float4*>(wb + 2 * WSTR + jp) = SL.xy;
    *reinterpret_cast<float4*>(wb + 3 * WSTR + jp) = SL.xx;
    if (lane < 4) {  // zero at image edges == pad semantics
      *reinterpret_cast<float4*>(wb + 0 * WSTR + hj) = HS.x;
      *reinterpret_cast<float4*>(wb + 1 * WSTR + hj) = HS.y;
      *reinterpret_cast<float4*>(wb + 2 * WSTR + hj) = HS.xy;
      *reinterpret_cast<float4*>(wb + 3 * WSTR + hj) = HS.xx;
    }
    // intra-wave DS in-order + compiler lgkmcnt: reads see the writes

    float av[4], bv[4];
    compute_ab_w(wb, j0, inv_cnt(p), invcx, av, bv);
    *reinterpret_cast<float4*>(as + (size_t)p * W + c0) = make_float4(av[0], av[1], av[2], av[3]);
    *reinterpret_cast<float4*>(bs + (size_t)p * W + c0) = make_float4(bv[0], bv[1], bv[2], bv[3]);

    vadd(SL, xa, ya);
    vsub(SL, xr, yr);
    if (lane < 4) { vadd(HS, hxa, hya); vsub(HS, hxr, hyr); }
  }
}

// ---------------------------------------------------------------------------
// Pass 2: out = box(a)/N * x + box(b)/N. Wave-private 2-stat stage, NO
// barriers. 32-row bands.
// ---------------------------------------------------------------------------
__global__ __launch_bounds__(256, 3) void k_out(
    const float* __restrict__ ag, const float* __restrict__ bg,
    const float* __restrict__ x, float* __restrict__ out) {
  __shared__ float stg[4][2][WSTR];  // [wave][a|b][272]  8.7 KB

  const int t = threadIdx.x;
  const int lane = t & 63;
  const int wid = t >> 6;
  const int wavebase = wid << 8;
  const int c0 = wavebase + (lane << 2);
  const int j0 = lane << 2;

  int slice, r0;
  map_block(blockIdx.x, slice, r0);
  const size_t soff = (size_t)slice * H * W;
  const float* as = ag + soff;
  const float* bs = bg + soff;
  const float* xs = x + soff;
  float* os = out + soff;

  const int hc = (lane < 2) ? (wavebase - 8 + (lane << 2))
                            : (wavebase + 256 + ((lane - 2) << 2));
  const bool hvalid = (lane < 4) && hc >= 0 && hc < W;
  const int hj = (lane < 2) ? (lane << 2) : (264 + ((lane - 2) << 2));

  float invcx[4];
  setup_invcx(c0, invcx);

  float4 Va = z4(), Vb = z4(), hVa = z4(), hVb = z4();
  {
    int lo = r0 - RAD < 0 ? 0 : r0 - RAD;
    for (int rr = lo; rr <= r0 + RAD; ++rr) {
      const float4 a4 = ldrow(as, rr, c0);
      const float4 b4 = ldrow(bs, rr, c0);
      Va.x += a4.x; Va.y += a4.y; Va.z += a4.z; Va.w += a4.w;
      Vb.x += b4.x; Vb.y += b4.y; Vb.z += b4.z; Vb.w += b4.w;
      if (hvalid) {
        const float4 ha4 = ldrow(as, rr, hc);
        const float4 hb4 = ldrow(bs, rr, hc);
        hVa.x += ha4.x; hVa.y += ha4.y; hVa.z += ha4.z; hVa.w += ha4.w;
        hVb.x += hb4.x; hVb.y += hb4.y; hVb.z += hb4.z; hVb.w += hb4.w;
      }
    }
  }

  float* wb = &stg[wid][0][0];
  for (int k = r0; k < r0 + ROWS; ++k) {
    const float4 xk = ldrow(xs, k, c0);
    float4 aa = z4(), ba = z4(), ar = z4(), br = z4();
    float4 haa = z4(), hba = z4(), har = z4(), hbr = z4();
    if (k + 9 <= H - 1) {
      aa = ldrow(as, k + 9, c0); ba = ldrow(bs, k + 9, c0);
      if (hvalid) { haa = ldrow(as, k + 9, hc); hba = ldrow(bs, k + 9, hc); }
    }
    if (k - RAD >= 0) {
      ar = ldrow(as, k - RAD, c0); br = ldrow(bs, k - RAD, c0);
      if (hvalid) { har = ldrow(as, k - RAD, hc); hbr = ldrow(bs, k - RAD, hc); }
    }

    const int jp = 8 + (lane << 2);
    *reinterpret_cast<float4*>(wb + 0 * WSTR + jp) = Va;
    *reinterpret_cast<float4*>(wb + 1 * WSTR + jp) = Vb;
    if (lane < 4) {
      *reinterpret_cast<float4*>(wb + 0 * WSTR + hj) = hVa;
      *reinterpret_cast<float4*>(wb + 1 * WSTR + hj) = hVb;
    }

    float HA[4], HB[4];
    hbox(wb + 0 * WSTR, j0, HA);
    hbox(wb + 1 * WSTR, j0, HB);

    const float invcy = inv_cnt(k);
    const float n0 = invcy * invcx[0], n1 = invcy * invcx[1];
    const float n2 = invcy * invcx[2], n3 = invcy * invcx[3];
    float4 o;
    o.x = HA[0] * n0 * xk.x + HB[0] * n0;
    o.y = HA[1] * n1 * xk.y + HB[1] * n1;
    o.z = HA[2] * n2 * xk.z + HB[2] * n2;
    o.w = HA[3] * n3 * xk.w + HB[3] * n3;
    *reinterpret_cast<float4*>(os + (size_t)k * W + c0) = o;

    Va.x += aa.x - ar.x; Va.y += aa.y - ar.y; Va.z += aa.z - ar.z; Va.w += aa.w - ar.w;
    Vb.x += ba.x - br.x; Vb.y += ba.y - br.y; Vb.z += ba.z - br.z; Vb.w += ba.w - br.w;
    if (hvalid) {
      hVa.x += haa.x - har.x; hVa.y += haa.y - har.y; hVa.z += haa.z - har.z; hVa.w += haa.w - har.w;
      hVb.x += hba.x - hbr.x; hVb.y += hba.y - hbr.y; hVb.z += hba.z - hbr.z; hVb.w += hba.w - hbr.w;
    }
  }
}

// ---------------------------------------------------------------------------
// Fallback: the previous verified fused kernel (dual-pipeline recompute),
// used when the workspace cannot hold the a,b intermediate (201 MB).
// ---------------------------------------------------------------------------
__device__ __forceinline__ void publish(float* fbase, int c0, const V4& S) {
  *reinterpret_cast<float4*>(&fbase[0 * PW + RAD + c0]) = S.x;
  *reinterpret_cast<float4*>(&fbase[1 * PW + RAD + c0]) = S.y;
  *reinterpret_cast<float4*>(&fbase[2 * PW + RAD + c0]) = S.xy;
  *reinterpret_cast<float4*>(&fbase[3 * PW + RAD + c0]) = S.xx;
}

__device__ __forceinline__ void compute_ab(const float* fbase, int c0, float invcy,
                                           const float invcx[4], float av[4], float bv[4]) {
  float bx[4], by[4], bxy[4], bxx[4];
  hbox(fbase + 0 * PW, c0, bx);
  hbox(fbase + 1 * PW, c0, by);
  hbox(fbase + 2 * PW, c0, bxy);
  hbox(fbase + 3 * PW, c0, bxx);
#pragma unroll
  for (int j = 0; j < 4; ++j) {
    const float invN = invcy * invcx[j];
    const float mx = bx[j] * invN;
    const float my = by[j] * invN;
    const float cov = bxy[j] * invN - mx * my;
    const float var = bxx[j] * invN - mx * mx;
    const float a = cov * frcp(var + EPS_C);
    av[j] = a;
    bv[j] = my - a * mx;
  }
}

__device__ __forceinline__ void publish2(float* sbase, int c0, const float av[4], const float bv[4]) {
  *reinterpret_cast<float4*>(&sbase[RAD + c0]) = make_float4(av[0], av[1], av[2], av[3]);
  *reinterpret_cast<float4*>(&sbase[PW + RAD + c0]) = make_float4(bv[0], bv[1], bv[2], bv[3]);
}

__device__ __forceinline__ void hbox2(const float* sbase, int c0, float HA[4], float HB[4]) {
  hbox(sbase, c0, HA);
  hbox(sbase + PW, c0, HB);
}

__global__ __launch_bounds__(256, 3) void k_fused(
    const float* __restrict__ x, const float* __restrict__ y, float* __restrict__ out) {
  __shared__ float stage[12 * PW];  // 49,920 B: fL[4] fG[4] sL[2] sG[2]
  float* fL = stage;
  float* fG = stage + 4 * PW;
  float* sL = stage + 8 * PW;
  float* sG = stage + 10 * PW;

  const int t = threadIdx.x;
  int slice, r0;
  map_block(blockIdx.x, slice, r0);
  const size_t soff = (size_t)slice * H * W;
  const float* xs = x + soff;
  const float* ys = y + soff;
  float* os = out + soff;
  const int c0 = t << 2;

  if (t < 96) {
    const int j = t >> 3, tt = t & 7;
    stage[j * PW + tt] = 0.f;
    stage[j * PW + W + RAD + tt] = 0.f;
  }

  float invcx[4];
  setup_invcx(c0, invcx);

  const int cstart = (r0 - 9 < 0) ? 0 : (r0 - 9);
  V4 SL; vzero(SL);
  {
    int lo = cstart - RAD; if (lo < 0) lo = 0;
    for (int rr = lo; rr <= cstart + RAD; ++rr) {
      vadd(SL, ldrow(xs, rr, c0), ldrow(ys, rr, c0));
    }
  }
  V4 SG;
  if (r0 == 0) vzero(SG); else SG = SL;
  float4 Sa = z4(), Sb = z4();

  __syncthreads();

  for (int c = cstart; c <= r0 + 7; ++c) {
    const float4 xa = ldrow(xs, c + 9, c0), ya = ldrow(ys, c + 9, c0);
    float4 xr = z4(), yr = z4();
    if (c - RAD >= 0) { xr = ldrow(xs, c - RAD, c0); yr = ldrow(ys, c - RAD, c0); }

    publish(fL, c0, SL);
    __syncthreads();
    float av[4], bv[4];
    compute_ab(fL, c0, inv_cnt(c), invcx, av, bv);
    publish2(sL, c0, av, bv);
    __syncthreads();
    float HA[4], HB[4];
    hbox2(sL, c0, HA, HB);
    Sa.x += HA[0]; Sa.y += HA[1]; Sa.z += HA[2]; Sa.w += HA[3];
    Sb.x += HB[0]; Sb.y += HB[1]; Sb.z += HB[2]; Sb.w += HB[3];
    vadd(SL, xa, ya);
    vsub(SL, xr, yr);
    __syncthreads();
  }

  for (int k = r0; k < r0 + ROWS; ++k) {
    const float4 xk = ldrow(xs, k, c0), yk = ldrow(ys, k, c0);
    float4 xt = z4(), yt = z4(), xb = z4(), yb = z4();
    if (k + 17 < H)  { xt = ldrow(xs, k + 17, c0); yt = ldrow(ys, k + 17, c0); }
    if (k - 17 >= 0) { xb = ldrow(xs, k - 17, c0); yb = ldrow(ys, k - 17, c0); }

    publish(fL, c0, SL);
    publish(fG, c0, SG);
    __syncthreads();  // A

    const int p = k + 8, q = k - 9;
    float avL[4], bvL[4], avG[4], bvG[4];
    compute_ab(fL, c0, inv_cnt(p), invcx, avL, bvL);
    compute_ab(fG, c0, inv_cnt(q), invcx, avG, bvG);
    publish2(sL, c0, avL, bvL);
    publish2(sG, c0, avG, bvG);
    __syncthreads();  // B

    float HAL[4], HBL[4], HAG[4], HBG[4];
    hbox2(sL, c0, HAL, HBL);
    hbox2(sG, c0, HAG, HBG);
    if (p <= H - 1) {
      Sa.x += HAL[0]; Sa.y += HAL[1]; Sa.z += HAL[2]; Sa.w += HAL[3];
      Sb.x += HBL[0]; Sb.y += HBL[1]; Sb.z += HBL[2]; Sb.w += HBL[3];
    }
    if (q >= 0) {
      Sa.x -= HAG[0]; Sa.y -= HAG[1]; Sa.z -= HAG[2]; Sa.w -= HAG[3];
      Sb.x -= HBG[0]; Sb.y -= HBG[1]; Sb.z -= HBG[2]; Sb.w -= HBG[3];
    }

    const float invcy = inv_cnt(k);
    const float n0 = invcy * invcx[0], n1 = invcy * invcx[1];
    const float n2 = invcy * invcx[2], n3 = invcy * invcx[3];
    float4 o;
    o.x = Sa.x * n0 * xk.x + Sb.x * n0;
    o.y = Sa.y * n1 * xk.y + Sb.y * n1;
    o.z = Sa.z * n2 * xk.z + Sb.z * n2;
    o.w = Sa.w * n3 * xk.w + Sb.w * n3;
    *reinterpret_cast<float4*>(os + (size_t)k * W + c0) = o;

    vadd(SL, xt, yt);
    vsub(SL, xk, yk);
    vadd(SG, xk, yk);
    vsub(SG, xb, yb);
    __syncthreads();  // C
  }
}

extern "C" void kernel_launch(void* const* d_in, const int* in_sizes, int n_in,
                              void* d_out, int out_size, void* d_ws, size_t ws_size,
                              hipStream_t stream) {
  const float* x = (const float*)d_in[0];
  const float* y = (const float*)d_in[1];
  float* out = (float*)d_out;
  const size_t need = 2 * IMG * sizeof(float);  // a,b intermediates (201 MB)
  if (d_ws != nullptr && ws_size >= need) {
    float* ag = (float*)d_ws;
    float* bg = ag + IMG;
    k_ab<<<GRID, 256, 0, stream>>>(x, y, ag, bg);
    k_out<<<GRID, 256, 0, stream>>>(ag, bg, x, out);
  } else {
    k_fused<<<GRID, 256, 0, stream>>>(x, y, out);
  }
}